// Round 1
// baseline (172.817 us; speedup 1.0000x reference)
//
#include <hip/hip_runtime.h>

#define LOG2E 1.4426950408889634f
#define K_SCALE 2.8853900817779268f   // 2*log2(e)

constexpr int Bn = 4, LXn = 384, LYn = 384, Hn = 256, Fn = 512;

// Fused dual GEMM: C[m,n] = K_SCALE * sum_f A[m,f]*B[n,f]
//  blocks [0,192):  A=y  (M=1536 rows b*LY+j), B=Wm (N=256 h)  -> pyK[(b*LY+j)*256 + h]
//  blocks [192,384): A=Wm (M=256 h), B=x (N=1536 cols b*LX+l)  -> pxT[b][h][l]
__global__ __launch_bounds__(256) void gemm12(
    const float* __restrict__ x, const float* __restrict__ y,
    const float* __restrict__ Wm, float* __restrict__ pxT, float* __restrict__ pyK)
{
  constexpr int BM = 32, BN = 64, BK = 16;
  __shared__ __align__(16) float As[BK][BM + 2];   // pad 34: 2-way max on store
  __shared__ __align__(16) float Bs[BK][BN + 4];   // pad 68: keeps float4 align, 2-way max
  int id = blockIdx.x;
  const float *Ap, *Bp;
  int m0, n0, mode;
  if (id < 192) { mode = 0; Ap = y;  Bp = Wm; m0 = (id % 48) * BM; n0 = (id / 48) * BN; }
  else { id -= 192; mode = 1; Ap = Wm; Bp = x; m0 = (id % 8) * BM; n0 = (id / 8) * BN; }

  const int tid = threadIdx.x;
  const int am = tid >> 3, af = (tid & 7) * 2;   // A tile: 32 rows x 16 k, float2 each
  const int bn = tid >> 2, bf = (tid & 3) * 4;   // B tile: 64 rows x 16 k, float4 each
  const int tx = tid & 15, ty = tid >> 4;        // micro: 2(m) x 4(n)

  const float* aptr = Ap + (m0 + am) * Fn + af;
  const float* bptr = Bp + (n0 + bn) * Fn + bf;
  float2 av = *(const float2*)aptr;
  float4 bv = *(const float4*)bptr;
  float acc[2][4] = {};

  for (int k0 = 0; k0 < Fn; k0 += BK) {
    __syncthreads();
    As[af][am] = av.x; As[af + 1][am] = av.y;
    Bs[bf][bn] = bv.x; Bs[bf + 1][bn] = bv.y; Bs[bf + 2][bn] = bv.z; Bs[bf + 3][bn] = bv.w;
    __syncthreads();
    if (k0 + BK < Fn) {                       // prefetch next tile; hides L2 latency under FMAs
      av = *(const float2*)(aptr + k0 + BK);
      bv = *(const float4*)(bptr + k0 + BK);
    }
    #pragma unroll
    for (int k = 0; k < BK; ++k) {
      float a0 = As[k][ty * 2], a1 = As[k][ty * 2 + 1];
      float4 b4 = *(const float4*)&Bs[k][tx * 4];
      acc[0][0] = fmaf(a0, b4.x, acc[0][0]);
      acc[0][1] = fmaf(a0, b4.y, acc[0][1]);
      acc[0][2] = fmaf(a0, b4.z, acc[0][2]);
      acc[0][3] = fmaf(a0, b4.w, acc[0][3]);
      acc[1][0] = fmaf(a1, b4.x, acc[1][0]);
      acc[1][1] = fmaf(a1, b4.y, acc[1][1]);
      acc[1][2] = fmaf(a1, b4.z, acc[1][2]);
      acc[1][3] = fmaf(a1, b4.w, acc[1][3]);
    }
  }

  #pragma unroll
  for (int i = 0; i < 2; ++i) {
    float4 r = make_float4(acc[i][0] * K_SCALE, acc[i][1] * K_SCALE,
                           acc[i][2] * K_SCALE, acc[i][3] * K_SCALE);
    int m = m0 + ty * 2 + i;
    if (mode == 0) {
      *(float4*)&pyK[m * Hn + n0 + tx * 4] = r;
    } else {
      int nb = n0 + tx * 4;
      int bb = nb / LXn, l = nb % LXn;        // 384 % 64 == 0: tile never straddles b
      *(float4*)&pxT[bb * (Hn * LXn) + m * LXn + l] = r;
    }
  }
}

// One block per (b, group of TJ=6 j rows); thread = l in [0,384).
// score[l] = -sum_h vm2[h]/(exp2(pxK - pyK)+1)   (softmax shift-invariant: drop sum(vm))
__global__ __launch_bounds__(384) void attn2(
    const float* __restrict__ pxT, const float* __restrict__ pyK,
    const float* __restrict__ vm, const float* __restrict__ x,
    float* __restrict__ out)
{
  constexpr int TJ = 6;
  __shared__ __align__(16) float py_s[TJ][Hn];
  __shared__ float vm2_s[Hn];
  __shared__ __align__(16) float a_s[TJ][LXn];
  __shared__ float redA[TJ][8];
  __shared__ float redB[TJ][8];

  const int tid = threadIdx.x;
  const int b = blockIdx.y;
  const int j0 = blockIdx.x * TJ;

  for (int i = tid; i < TJ * Hn; i += 384)
    py_s[i >> 8][i & 255] = pyK[(size_t)(b * LYn + j0 + (i >> 8)) * Hn + (i & 255)];
  if (tid < Hn) vm2_s[tid] = 2.0f * vm[tid];
  __syncthreads();

  // ---- phase B: scores ----
  const int l = tid;
  const float* pxp = pxT + (size_t)b * Hn * LXn + l;
  float s[TJ] = {0, 0, 0, 0, 0, 0};
  #pragma unroll 4
  for (int h = 0; h < Hn; ++h) {
    float pxv = pxp[h * LXn];          // coalesced; pxT[b] (384KB) L2-resident
    float v2 = vm2_s[h];               // LDS broadcast
    #pragma unroll
    for (int jj = 0; jj < TJ; ++jj) {
      float e = __builtin_amdgcn_exp2f(pxv - py_s[jj][h]);
      s[jj] = fmaf(v2, __builtin_amdgcn_rcpf(e + 1.0f), s[jj]);
    }
  }

  // ---- phase C: softmax over l (384 threads = 6 waves) ----
  const int lane = tid & 63, wid = tid >> 6;
  float ee[TJ];
  #pragma unroll
  for (int jj = 0; jj < TJ; ++jj) {
    float v = -s[jj];
    #pragma unroll
    for (int off = 32; off > 0; off >>= 1) v = fmaxf(v, __shfl_xor(v, off));
    if (lane == 0) redA[jj][wid] = v;
  }
  __syncthreads();
  #pragma unroll
  for (int jj = 0; jj < TJ; ++jj) {
    float v = redA[jj][0];
    #pragma unroll
    for (int w = 1; w < 6; ++w) v = fmaxf(v, redA[jj][w]);
    float e = __builtin_amdgcn_exp2f((-s[jj] - v) * LOG2E);
    ee[jj] = e;
    #pragma unroll
    for (int off = 32; off > 0; off >>= 1) e += __shfl_xor(e, off);
    if (lane == 0) redB[jj][wid] = e;
  }
  __syncthreads();
  #pragma unroll
  for (int jj = 0; jj < TJ; ++jj) {
    float t = redB[jj][0];
    #pragma unroll
    for (int w = 1; w < 6; ++w) t += redB[jj][w];
    a_s[jj][l] = ee[jj] * __builtin_amdgcn_rcpf(t);
  }
  __syncthreads();

  // ---- phase D: qtm[b,j,f] = sum_l a[l] * x[b,l,f] ----
  const float* xb = x + (size_t)b * LXn * Fn;
  float acc0[TJ] = {}, acc1[TJ] = {};
  const bool hi = tid < (Fn - LXn);   // first 128 threads also cover f in [384,512)
  for (int ll = 0; ll < LXn; ll += 4) {
    float4 aa[TJ];
    #pragma unroll
    for (int jj = 0; jj < TJ; ++jj) aa[jj] = *(const float4*)&a_s[jj][ll];
    #pragma unroll
    for (int u = 0; u < 4; ++u) {
      float xv = xb[(size_t)(ll + u) * Fn + tid];
      #pragma unroll
      for (int jj = 0; jj < TJ; ++jj)
        acc0[jj] = fmaf(((const float*)&aa[jj])[u], xv, acc0[jj]);
    }
    if (hi) {
      #pragma unroll
      for (int u = 0; u < 4; ++u) {
        float xv = xb[(size_t)(ll + u) * Fn + LXn + tid];
        #pragma unroll
        for (int jj = 0; jj < TJ; ++jj)
          acc1[jj] = fmaf(((const float*)&aa[jj])[u], xv, acc1[jj]);
      }
    }
  }
  float* ob = out + ((size_t)b * LYn + j0) * Fn;
  #pragma unroll
  for (int jj = 0; jj < TJ; ++jj) ob[jj * Fn + tid] = acc0[jj];
  if (hi) {
    #pragma unroll
    for (int jj = 0; jj < TJ; ++jj) ob[jj * Fn + LXn + tid] = acc1[jj];
  }
}

extern "C" void kernel_launch(void* const* d_in, const int* in_sizes, int n_in,
                              void* d_out, int out_size, void* d_ws, size_t ws_size,
                              hipStream_t stream) {
  const float* x  = (const float*)d_in[0];
  const float* y  = (const float*)d_in[1];
  const float* Wm = (const float*)d_in[2];
  const float* vm = (const float*)d_in[3];
  float* outp = (float*)d_out;
  float* pxT = (float*)d_ws;                    // [B][H][LX] = 393216 floats
  float* pyK = pxT + (size_t)Bn * Hn * LXn;     // [B][LY][H] = 393216 floats (3 MB total ws)

  hipLaunchKernelGGL(gemm12, dim3(384), dim3(256), 0, stream, x, y, Wm, pxT, pyK);
  hipLaunchKernelGGL(attn2, dim3(LYn / 6, Bn), dim3(384), 0, stream, pxT, pyK, vm, x, outp);
}

// Round 2
// 168.226 us; speedup vs baseline: 1.0273x; 1.0273x over previous
//
#include <hip/hip_runtime.h>

#define LOG2E 1.4426950408889634f
#define K_SCALE 2.8853900817779268f   // 2*log2(e)

constexpr int Bn = 4, LXn = 384, LYn = 384, Hn = 256, Fn = 512;
constexpr int Kc = 128;               // k-chunk staged in LDS

// SGPR-broadcast dual GEMM with exp2 epilogue.
//  job0 (id<96):  ey[(b*LY+j)][h] = exp2(-K * sum_k y[j,k]*Wm[h,k])
//                 lane-dim = h (LDS-staged Wm^T), SGPR-dim = y rows
//  job1 (id>=96): exT[b][h][l]    = exp2(+K * sum_k x[l,k]*Wm[h,k])
//                 lane-dim = l (LDS-staged x^T),  SGPR-dim = Wm rows
// Per wave: 64 lane-outputs x 16 SGPR-rows. 1 ds_read_b32 per 16 FMAs ->
// VALU-bound, not LDS-bound (the R1 gemm12 failure mode).
__global__ __launch_bounds__(256) void gemm_sb(
    const float* __restrict__ x, const float* __restrict__ y,
    const float* __restrict__ Wm, float* __restrict__ exT, float* __restrict__ ey)
{
  __shared__ float S[Kc][65];   // [k][r], pad 65: S[k][lane] reads conflict-free
  int id = blockIdx.x;
  const float *Sp, *Tp;
  float* Cp; int cstride; float ksc;
  if (id < 96) {
    int r0 = (id & 3) * 64;                     // h tile
    int t0 = (id >> 2) * 64;                    // j tile (global over b*LY)
    Sp = Wm + (size_t)r0 * Fn;
    Tp = y + (size_t)t0 * Fn;
    Cp = ey + (size_t)t0 * Hn + r0;
    cstride = Hn; ksc = -K_SCALE;
  } else {
    id -= 96;
    int r0 = (id >> 2) * 64;                    // l tile (global over b*LX)
    int t0 = (id & 3) * 64;                     // h tile
    Sp = x + (size_t)r0 * Fn;
    Tp = Wm + (size_t)t0 * Fn;
    int bb = r0 / LXn, lloc = r0 % LXn;         // 64 | 384: never straddles b
    Cp = exT + (size_t)bb * Hn * LXn + (size_t)t0 * LXn + lloc;
    cstride = LXn; ksc = K_SCALE;
  }
  const int tid = threadIdx.x;
  const int lane = tid & 63;
  const int wvu = __builtin_amdgcn_readfirstlane(tid >> 6);  // force scalar view
  const float* Tw = Tp + (size_t)wvu * 16 * Fn;
  float acc[16] = {};

  for (int kc = 0; kc < Fn; kc += Kc) {
    __syncthreads();
    // stage S rows transposed: 64 rows x Kc k = 2048 float4 / 256 threads
    #pragma unroll
    for (int u = 0; u < 8; ++u) {
      int idx = tid + u * 256;
      int r = idx >> 5;              // Kc/4 = 32 float4 per row
      int k4 = (idx & 31) * 4;
      const float4 v = *(const float4*)(Sp + (size_t)r * Fn + kc + k4);
      S[k4 + 0][r] = v.x; S[k4 + 1][r] = v.y; S[k4 + 2][r] = v.z; S[k4 + 3][r] = v.w;
    }
    __syncthreads();
    const float* Tk = Tw + kc;
    #pragma unroll 2
    for (int k = 0; k < Kc; k += 4) {
      float a0 = S[k][lane], a1 = S[k + 1][lane], a2 = S[k + 2][lane], a3 = S[k + 3][lane];
      #pragma unroll
      for (int nn = 0; nn < 16; ++nn) {
        const float* tr = Tk + (size_t)nn * Fn + k;   // wave-uniform -> s_load_dwordx4
        acc[nn] = fmaf(a3, tr[3], fmaf(a2, tr[2], fmaf(a1, tr[1], fmaf(a0, tr[0], acc[nn]))));
      }
    }
  }
  #pragma unroll
  for (int nn = 0; nn < 16; ++nn)
    Cp[(size_t)(wvu * 16 + nn) * cstride + lane] = __builtin_amdgcn_exp2f(ksc * acc[nn]);
}

// One block per (b, 6 j-rows); 768 threads = 12 waves.
// Phase B: thread (l = tid%384, half = tid/384) accumulates h in [half*128, half*128+128):
//   s'[l,jj] = sum_h vm[h] * rcp(ex[h,l]*ey[jj,h] + 1)    (1 trans op / element)
// tanh identity: sjt = sum(vm) - 2 s'; softmax shift-invariance drops sum(vm).
__global__ __launch_bounds__(768) void attn2(
    const float* __restrict__ exT, const float* __restrict__ ey,
    const float* __restrict__ vm, const float* __restrict__ x,
    float* __restrict__ out)
{
  __shared__ __align__(16) float sp[6][384];   // partial-s, then attention weights
  __shared__ float redA[6][8], redB[6][8];
  const int tid = threadIdx.x;
  const int b = blockIdx.y;
  const int j0 = blockIdx.x * 6;
  const int l = tid % 384;
  const int hoff = __builtin_amdgcn_readfirstlane((tid / 384) * 128);
  const float* exb = exT + (size_t)b * Hn * LXn + (size_t)hoff * LXn + l;
  const float* eyu = ey + ((size_t)b * LYn + j0) * Hn + hoff;   // uniform -> s_load
  const float* vmu = vm + hoff;                                 // uniform -> s_load
  float s[6] = {0, 0, 0, 0, 0, 0};

  for (int h = 0; h < 128; h += 8) {
    float exv[8];
    #pragma unroll
    for (int u = 0; u < 8; ++u) exv[u] = exb[(size_t)(h + u) * LXn];  // 8 loads in flight
    #pragma unroll
    for (int u = 0; u < 8; ++u) {
      float w = vmu[h + u];
      #pragma unroll
      for (int jj = 0; jj < 6; ++jj) {
        float E = exv[u] * eyu[jj * Hn + h + u];
        s[jj] = fmaf(w, __builtin_amdgcn_rcpf(E + 1.0f), s[jj]);
      }
    }
  }

  if (tid >= 384) {
    #pragma unroll
    for (int jj = 0; jj < 6; ++jj) sp[jj][l] = s[jj];
  }
  __syncthreads();

  const int lane = tid & 63, wid = tid >> 6;
  float v[6], ee[6];
  if (tid < 384) {
    #pragma unroll
    for (int jj = 0; jj < 6; ++jj) {
      float t = -2.0f * (s[jj] + sp[jj][l]);
      v[jj] = t;
      #pragma unroll
      for (int off = 32; off > 0; off >>= 1) t = fmaxf(t, __shfl_xor(t, off));
      if (lane == 0) redA[jj][wid] = t;
    }
  }
  __syncthreads();
  if (tid < 384) {
    #pragma unroll
    for (int jj = 0; jj < 6; ++jj) {
      float m = redA[jj][0];
      #pragma unroll
      for (int w = 1; w < 6; ++w) m = fmaxf(m, redA[jj][w]);
      float e = __builtin_amdgcn_exp2f((v[jj] - m) * LOG2E);
      ee[jj] = e;
      #pragma unroll
      for (int off = 32; off > 0; off >>= 1) e += __shfl_xor(e, off);
      if (lane == 0) redB[jj][wid] = e;
    }
  }
  __syncthreads();
  if (tid < 384) {
    #pragma unroll
    for (int jj = 0; jj < 6; ++jj) {
      float t = redB[jj][0];
      #pragma unroll
      for (int w = 1; w < 6; ++w) t += redB[jj][w];
      sp[jj][l] = ee[jj] * __builtin_amdgcn_rcpf(t);
    }
  }
  __syncthreads();

  // Phase D: qtm[b,j,f] = sum_l a[jj][l] * x[b,l,f]; waves 0-7 active, f = tid.
  if (tid < 512) {
    const float* xb = x + (size_t)b * LXn * Fn + tid;
    float acc[6] = {};
    for (int ll = 0; ll < LXn; ll += 4) {
      float4 aa[6];
      #pragma unroll
      for (int jj = 0; jj < 6; ++jj) aa[jj] = *(const float4*)&sp[jj][ll];
      #pragma unroll
      for (int u = 0; u < 4; ++u) {
        float xv = xb[(size_t)(ll + u) * Fn];
        #pragma unroll
        for (int jj = 0; jj < 6; ++jj)
          acc[jj] = fmaf(((const float*)&aa[jj])[u], xv, acc[jj]);
      }
    }
    float* ob = out + ((size_t)b * LYn + j0) * Fn + tid;
    #pragma unroll
    for (int jj = 0; jj < 6; ++jj) ob[(size_t)jj * Fn] = acc[jj];
  }
}

extern "C" void kernel_launch(void* const* d_in, const int* in_sizes, int n_in,
                              void* d_out, int out_size, void* d_ws, size_t ws_size,
                              hipStream_t stream) {
  const float* x  = (const float*)d_in[0];
  const float* y  = (const float*)d_in[1];
  const float* Wm = (const float*)d_in[2];
  const float* vm = (const float*)d_in[3];
  float* outp = (float*)d_out;
  float* exT = (float*)d_ws;                       // [B][H][LX] floats
  float* eyB = exT + (size_t)Bn * Hn * LXn;        // [B*LY][H] floats (3 MB total)

  hipLaunchKernelGGL(gemm_sb, dim3(192), dim3(256), 0, stream, x, y, Wm, exT, eyB);
  hipLaunchKernelGGL(attn2, dim3(LYn / 6, Bn), dim3(768), 0, stream, exT, eyB, vm, x, outp);
}

// Round 3
// 136.453 us; speedup vs baseline: 1.2665x; 1.2329x over previous
//
#include <hip/hip_runtime.h>

#define LOG2E 1.4426950408889634f
#define K_SCALE 2.8853900817779268f   // 2*log2(e)

constexpr int Bn = 4, LXn = 384, LYn = 384, Hn = 256, Fn = 512;
constexpr int Mrows = 1536;                 // Bn*LXn == Bn*LYn
constexpr int KS = 4, KCHUNK = 128;         // K split
constexpr size_t Pstride = (size_t)Mrows * Hn;   // 393216 floats per ks slice

// ws layout (floats):
//   P   [2][KS][...]  @ 0          (2*4*393216 = 3145728)  -- GEMM partials
//   ey  [1536][256]   @ 3145728
//   exT [4][256][384] @ 3538944
//   s   [4][384][384] @ 0          (aliases P0; P dead after reduce_exp2)

// ---------------------------------------------------------------- kernel 1
// Partial GEMM, K split 4-way. 768 blocks x 256 threads (12 waves/CU).
//  t<96 : C0[m,h] = sum_k y[m,k]*Wm[h,k]   (m over 1536)
//  t>=96: C1[h,n] = sum_k Wm[h,k]*x[n,k]   (n over 1536; h-major so the
//                                           downstream ex access needs no transpose)
__global__ __launch_bounds__(256) void gemm_part(
    const float* __restrict__ x, const float* __restrict__ y,
    const float* __restrict__ Wm, float* __restrict__ P)
{
  __shared__ float As[32][68], Bs[32][68];   // [k][row]; 68*4B=272B keeps 16B align
  const int bid = blockIdx.x;
  const int ks = bid & 3;
  int t = bid >> 2;
  const float *Aop, *Bop; float* Cp; int cstr;
  if (t < 96) {
    int m0 = (t % 24) * 64, n0 = (t / 24) * 64;
    Aop = y + (size_t)m0 * Fn; Bop = Wm + (size_t)n0 * Fn;
    Cp = P + (size_t)ks * Pstride + (size_t)m0 * Hn + n0; cstr = Hn;
  } else {
    t -= 96;
    int m0 = (t & 3) * 64, n0 = (t >> 2) * 64;
    Aop = Wm + (size_t)m0 * Fn; Bop = x + (size_t)n0 * Fn;
    Cp = P + (size_t)(KS + ks) * Pstride + (size_t)m0 * Mrows + n0; cstr = Mrows;
  }
  const int tid = threadIdx.x;
  const int tx = tid & 15, ty = tid >> 4;        // 4x4 micro-tile coords
  const int r0 = tid >> 3, k4 = (tid & 7) * 4;   // staging: row r0/r0+32, k-quad k4
  const int kbase = ks * KCHUNK;

  const float* ap = Aop + (size_t)r0 * Fn + kbase + k4;
  const float* bp = Bop + (size_t)r0 * Fn + kbase + k4;
  float4 a0 = *(const float4*)ap;
  float4 a1 = *(const float4*)(ap + 32 * Fn);
  float4 b0 = *(const float4*)bp;
  float4 b1 = *(const float4*)(bp + 32 * Fn);
  float acc[4][4] = {};

  for (int kk = 0; kk < 4; ++kk) {               // 4 chunks of 32 k
    __syncthreads();
    As[k4 + 0][r0] = a0.x; As[k4 + 1][r0] = a0.y; As[k4 + 2][r0] = a0.z; As[k4 + 3][r0] = a0.w;
    As[k4 + 0][r0 + 32] = a1.x; As[k4 + 1][r0 + 32] = a1.y; As[k4 + 2][r0 + 32] = a1.z; As[k4 + 3][r0 + 32] = a1.w;
    Bs[k4 + 0][r0] = b0.x; Bs[k4 + 1][r0] = b0.y; Bs[k4 + 2][r0] = b0.z; Bs[k4 + 3][r0] = b0.w;
    Bs[k4 + 0][r0 + 32] = b1.x; Bs[k4 + 1][r0 + 32] = b1.y; Bs[k4 + 2][r0 + 32] = b1.z; Bs[k4 + 3][r0 + 32] = b1.w;
    __syncthreads();
    if (kk < 3) {                                // prefetch next chunk
      a0 = *(const float4*)(ap + (kk + 1) * 32);
      a1 = *(const float4*)(ap + 32 * Fn + (kk + 1) * 32);
      b0 = *(const float4*)(bp + (kk + 1) * 32);
      b1 = *(const float4*)(bp + 32 * Fn + (kk + 1) * 32);
    }
    #pragma unroll
    for (int k = 0; k < 32; ++k) {
      float4 av = *(const float4*)&As[k][ty * 4];
      float4 bv = *(const float4*)&Bs[k][tx * 4];
      acc[0][0] = fmaf(av.x, bv.x, acc[0][0]); acc[0][1] = fmaf(av.x, bv.y, acc[0][1]);
      acc[0][2] = fmaf(av.x, bv.z, acc[0][2]); acc[0][3] = fmaf(av.x, bv.w, acc[0][3]);
      acc[1][0] = fmaf(av.y, bv.x, acc[1][0]); acc[1][1] = fmaf(av.y, bv.y, acc[1][1]);
      acc[1][2] = fmaf(av.y, bv.z, acc[1][2]); acc[1][3] = fmaf(av.y, bv.w, acc[1][3]);
      acc[2][0] = fmaf(av.z, bv.x, acc[2][0]); acc[2][1] = fmaf(av.z, bv.y, acc[2][1]);
      acc[2][2] = fmaf(av.z, bv.z, acc[2][2]); acc[2][3] = fmaf(av.z, bv.w, acc[2][3]);
      acc[3][0] = fmaf(av.w, bv.x, acc[3][0]); acc[3][1] = fmaf(av.w, bv.y, acc[3][1]);
      acc[3][2] = fmaf(av.w, bv.z, acc[3][2]); acc[3][3] = fmaf(av.w, bv.w, acc[3][3]);
    }
  }
  #pragma unroll
  for (int i = 0; i < 4; ++i) {
    float4 r = make_float4(acc[i][0], acc[i][1], acc[i][2], acc[i][3]);
    *(float4*)&Cp[(size_t)(ty * 4 + i) * cstr + tx * 4] = r;
  }
}

// ---------------------------------------------------------------- kernel 2
// Sum 4 K-partials + exp2 epilogue.  ey = exp2(-K*py), exT[b][h][l] = exp2(+K*px)
__global__ __launch_bounds__(256) void reduce_exp2(
    const float* __restrict__ P, float* __restrict__ ey, float* __restrict__ exT)
{
  const int g = blockIdx.x * 256 + threadIdx.x;    // [0, 196608) float4-quads
  if (g < 98304) {
    const size_t i = (size_t)g * 4;
    const float* p = P + i;
    float4 s0 = *(const float4*)p;
    float4 s1 = *(const float4*)(p + Pstride);
    float4 s2 = *(const float4*)(p + 2 * Pstride);
    float4 s3 = *(const float4*)(p + 3 * Pstride);
    float4 r;
    r.x = __builtin_amdgcn_exp2f(-K_SCALE * (s0.x + s1.x + s2.x + s3.x));
    r.y = __builtin_amdgcn_exp2f(-K_SCALE * (s0.y + s1.y + s2.y + s3.y));
    r.z = __builtin_amdgcn_exp2f(-K_SCALE * (s0.z + s1.z + s2.z + s3.z));
    r.w = __builtin_amdgcn_exp2f(-K_SCALE * (s0.w + s1.w + s2.w + s3.w));
    *(float4*)&ey[i] = r;
  } else {
    const int g2 = g - 98304;
    const size_t i = (size_t)g2 * 4;               // flat in [256][1536]
    const float* p = P + 4 * Pstride + i;
    float4 s0 = *(const float4*)p;
    float4 s1 = *(const float4*)(p + Pstride);
    float4 s2 = *(const float4*)(p + 2 * Pstride);
    float4 s3 = *(const float4*)(p + 3 * Pstride);
    float4 r;
    r.x = __builtin_amdgcn_exp2f(K_SCALE * (s0.x + s1.x + s2.x + s3.x));
    r.y = __builtin_amdgcn_exp2f(K_SCALE * (s0.y + s1.y + s2.y + s3.y));
    r.z = __builtin_amdgcn_exp2f(K_SCALE * (s0.z + s1.z + s2.z + s3.z));
    r.w = __builtin_amdgcn_exp2f(K_SCALE * (s0.w + s1.w + s2.w + s3.w));
    int h = (int)(i / Mrows), n = (int)(i % Mrows);
    int b = n / LXn, l = n % LXn;                  // quad never straddles b
    *(float4*)&exT[(size_t)b * Hn * LXn + (size_t)h * LXn + l] = r;
  }
}

// ---------------------------------------------------------------- kernel 3
// s[b,j,l] = sum_h (-2 vm_h) * rcp(ex[h,l]*ey[j,h] + 1)
// 2-way reciprocal pairing: va/A + vb/B = (va*B + vb*A) * rcp(A*B)
// Block: (b, 3 j's), thread = l. 512 blocks x 6 waves = 12 waves/CU.
__global__ __launch_bounds__(384) void score_k(
    const float* __restrict__ exT, const float* __restrict__ ey,
    const float* __restrict__ vm, float* __restrict__ sout)
{
  __shared__ float ey3[3][256];
  __shared__ float vm2[256];
  const int tid = threadIdx.x;
  const int b = blockIdx.y, j0 = blockIdx.x * 3;
  for (int i = tid; i < 768; i += 384)
    ey3[i >> 8][i & 255] = ey[(size_t)(b * LYn + j0 + (i >> 8)) * Hn + (i & 255)];
  if (tid < 256) vm2[tid] = -2.0f * vm[tid];
  __syncthreads();

  const float* exb = exT + (size_t)b * Hn * LXn + tid;
  float acc[3] = {0.f, 0.f, 0.f};
  for (int h = 0; h < Hn; h += 8) {
    float ev[8];
    #pragma unroll
    for (int u = 0; u < 8; ++u) ev[u] = exb[(size_t)(h + u) * LXn];  // 8 loads in flight
    float4 va = *(const float4*)&vm2[h];
    float4 vb = *(const float4*)&vm2[h + 4];
    #pragma unroll
    for (int jj = 0; jj < 3; ++jj) {
      float4 ea = *(const float4*)&ey3[jj][h];
      float4 eb = *(const float4*)&ey3[jj][h + 4];
      float A, B, num;
      A = fmaf(ev[0], ea.x, 1.f); B = fmaf(ev[1], ea.y, 1.f);
      num = fmaf(va.y, A, va.x * B);
      acc[jj] = fmaf(num, __builtin_amdgcn_rcpf(A * B), acc[jj]);
      A = fmaf(ev[2], ea.z, 1.f); B = fmaf(ev[3], ea.w, 1.f);
      num = fmaf(va.w, A, va.z * B);
      acc[jj] = fmaf(num, __builtin_amdgcn_rcpf(A * B), acc[jj]);
      A = fmaf(ev[4], eb.x, 1.f); B = fmaf(ev[5], eb.y, 1.f);
      num = fmaf(vb.y, A, vb.x * B);
      acc[jj] = fmaf(num, __builtin_amdgcn_rcpf(A * B), acc[jj]);
      A = fmaf(ev[6], eb.z, 1.f); B = fmaf(ev[7], eb.w, 1.f);
      num = fmaf(vb.w, A, vb.z * B);
      acc[jj] = fmaf(num, __builtin_amdgcn_rcpf(A * B), acc[jj]);
    }
  }
  #pragma unroll
  for (int jj = 0; jj < 3; ++jj)
    sout[(size_t)(b * LYn + j0 + jj) * LXn + tid] = acc[jj];
}

// ---------------------------------------------------------------- kernel 4
// Per-wave softmax (waves 0-5 own one j-row each: no cross-wave reduce),
// then qtm[b,j,f] = sum_l a[j][l] * x[b,l,f].  256 blocks x 8 waves.
__global__ __launch_bounds__(512) void softmax_qtm(
    const float* __restrict__ s, const float* __restrict__ x, float* __restrict__ out)
{
  __shared__ float a_s[6][384];
  const int tid = threadIdx.x;
  const int b = blockIdx.y, j0 = blockIdx.x * 6;
  const int wid = tid >> 6, lane = tid & 63;
  if (wid < 6) {
    const float* sr = s + (size_t)(b * LYn + j0 + wid) * LXn;
    float sv[6];
    #pragma unroll
    for (int q = 0; q < 6; ++q) sv[q] = sr[lane + 64 * q];
    float m = sv[0];
    #pragma unroll
    for (int q = 1; q < 6; ++q) m = fmaxf(m, sv[q]);
    #pragma unroll
    for (int off = 32; off; off >>= 1) m = fmaxf(m, __shfl_xor(m, off));
    float e[6], tot = 0.f;
    #pragma unroll
    for (int q = 0; q < 6; ++q) { e[q] = __builtin_amdgcn_exp2f((sv[q] - m) * LOG2E); tot += e[q]; }
    #pragma unroll
    for (int off = 32; off; off >>= 1) tot += __shfl_xor(tot, off);
    float r = __builtin_amdgcn_rcpf(tot);
    #pragma unroll
    for (int q = 0; q < 6; ++q) a_s[wid][lane + 64 * q] = e[q] * r;
  }
  __syncthreads();

  const float* xb = x + (size_t)b * LXn * Fn + tid;   // f = tid
  float acc[6] = {};
  for (int ll = 0; ll < LXn; ll += 16) {
    float xv[16];
    #pragma unroll
    for (int u = 0; u < 16; ++u) xv[u] = xb[(size_t)(ll + u) * Fn];
    #pragma unroll
    for (int u4 = 0; u4 < 4; ++u4) {
      #pragma unroll
      for (int jj = 0; jj < 6; ++jj) {
        float4 a4 = *(const float4*)&a_s[jj][ll + u4 * 4];
        acc[jj] = fmaf(a4.x, xv[u4 * 4 + 0], acc[jj]);
        acc[jj] = fmaf(a4.y, xv[u4 * 4 + 1], acc[jj]);
        acc[jj] = fmaf(a4.z, xv[u4 * 4 + 2], acc[jj]);
        acc[jj] = fmaf(a4.w, xv[u4 * 4 + 3], acc[jj]);
      }
    }
  }
  float* ob = out + (size_t)(b * LYn + j0) * Fn + tid;
  #pragma unroll
  for (int jj = 0; jj < 6; ++jj) ob[(size_t)jj * Fn] = acc[jj];
}

extern "C" void kernel_launch(void* const* d_in, const int* in_sizes, int n_in,
                              void* d_out, int out_size, void* d_ws, size_t ws_size,
                              hipStream_t stream) {
  const float* x  = (const float*)d_in[0];
  const float* y  = (const float*)d_in[1];
  const float* Wm = (const float*)d_in[2];
  const float* vm = (const float*)d_in[3];
  float* outp = (float*)d_out;

  float* P   = (float*)d_ws;                       // 3145728 floats (12.6 MB)
  float* ey  = P + 2 * KS * Pstride;               // 393216 floats
  float* exT = ey + Pstride;                       // 393216 floats
  float* sbf = P;                                  // alias P0 (dead after reduce_exp2)

  hipLaunchKernelGGL(gemm_part, dim3(768), dim3(256), 0, stream, x, y, Wm, P);
  hipLaunchKernelGGL(reduce_exp2, dim3(768), dim3(256), 0, stream, P, ey, exT);
  hipLaunchKernelGGL(score_k, dim3(128, 4), dim3(384), 0, stream, exT, ey, vm, sbf);
  hipLaunchKernelGGL(softmax_qtm, dim3(64, 4), dim3(512), 0, stream, sbf, x, outp);
}

// Round 4
// 115.723 us; speedup vs baseline: 1.4934x; 1.1791x over previous
//
#include <hip/hip_runtime.h>

#define LOG2E 1.4426950408889634f
#define K_SCALE 2.8853900817779268f   // 2*log2(e)

typedef __attribute__((ext_vector_type(8))) short bf16x8;
typedef __attribute__((ext_vector_type(4))) float f32x4;

constexpr int Bn = 4, LXn = 384, LYn = 384, Hn = 256, Fn = 512;

__device__ inline unsigned short bf16rn(float f) {
  unsigned u = __builtin_bit_cast(unsigned, f);
  u += 0x7fff + ((u >> 16) & 1);             // round-to-nearest-even
  return (unsigned short)(u >> 16);
}
__device__ inline float bf16tof(unsigned short h) {
  return __builtin_bit_cast(float, (unsigned)h << 16);
}

// ---------------------------------------------------------------- kernel 1
// blocks [0,96):   ey[m=(b,j)][h]  = exp2(-K * y.Wm^T)   (MFMA, split-bf16 3-product)
// blocks [96,192): exT[b][h][l]    = exp2(+K * Wm.x^T)
// blocks [192,384): transpose+split x -> xThi/xTlo[b][f][l]  (for kernel 3's B operand)
__global__ __launch_bounds__(256) void k1(
    const float* __restrict__ x, const float* __restrict__ y,
    const float* __restrict__ Wm, float* __restrict__ ey, float* __restrict__ exT,
    unsigned short* __restrict__ xThi, unsigned short* __restrict__ xTlo)
{
  __shared__ char smem[36864];
  const int tid = threadIdx.x;
  const int bid = blockIdx.x;

  if (bid >= 192) {                       // ---- transpose/split path ----
    float* T = (float*)smem;              // [64][65]
    const int pid = bid - 192;
    const int b = pid / 48, t = pid % 48;
    const int l0 = (t / 8) * 64, f0 = (t % 8) * 64;
    const int r = tid >> 2, cq = (tid & 3) * 16;
    const float* xp = x + ((size_t)(b * LXn + l0 + r)) * Fn + f0 + cq;
    #pragma unroll
    for (int q = 0; q < 4; ++q) {
      float4 v = *(const float4*)(xp + q * 4);
      T[r * 65 + cq + q * 4 + 0] = v.x; T[r * 65 + cq + q * 4 + 1] = v.y;
      T[r * 65 + cq + q * 4 + 2] = v.z; T[r * 65 + cq + q * 4 + 3] = v.w;
    }
    __syncthreads();
    const int fr = tid >> 2, lq = (tid & 3) * 16;
    unsigned short hi[16], lo[16];
    #pragma unroll
    for (int i = 0; i < 16; ++i) {
      float v = T[(lq + i) * 65 + fr];
      hi[i] = bf16rn(v);
      lo[i] = bf16rn(v - bf16tof(hi[i]));
    }
    size_t o = ((size_t)(b * Fn + f0 + fr)) * LXn + l0 + lq;
    *(uint4*)&xThi[o] = *(uint4*)&hi[0]; *(uint4*)&xThi[o + 8] = *(uint4*)&hi[8];
    *(uint4*)&xTlo[o] = *(uint4*)&lo[0]; *(uint4*)&xTlo[o + 8] = *(uint4*)&lo[8];
    return;
  }

  // ---- MFMA GEMM path ----
  unsigned short* Ah = (unsigned short*)smem;   // [64][72] bf16, pad 72 breaks conflicts
  unsigned short* Al = Ah + 64 * 72;
  unsigned short* Bh = Al + 64 * 72;
  unsigned short* Bl = Bh + 64 * 72;

  const float *Ap, *Bp; float ksc; bool jobA;
  int m0, n0;
  if (bid < 96) { jobA = true;  int mt = bid % 24, nt = bid / 24; m0 = mt * 64; n0 = nt * 64;
                  Ap = y;  Bp = Wm; ksc = -K_SCALE; }
  else          { jobA = false; int t = bid - 96; int mt = t & 3, nt = t >> 2; m0 = mt * 64; n0 = nt * 64;
                  Ap = Wm; Bp = x;  ksc =  K_SCALE; }

  const int r = tid >> 2, kq = (tid & 3) * 16;
  const int w = tid >> 6, lane = tid & 63, quad = lane >> 4, l15 = lane & 15;
  const int mo = (w & 1) * 32, no = (w >> 1) * 32;   // wave tile 32x32
  f32x4 acc[2][2] = {};

  for (int kc = 0; kc < Fn; kc += 64) {
    __syncthreads();
    {
      const float* ap = Ap + ((size_t)(m0 + r)) * Fn + kc + kq;
      unsigned short hi[16], lo[16];
      #pragma unroll
      for (int q = 0; q < 4; ++q) {
        float4 v = *(const float4*)(ap + q * 4);
        float vv[4] = {v.x, v.y, v.z, v.w};
        #pragma unroll
        for (int i = 0; i < 4; ++i) {
          hi[q * 4 + i] = bf16rn(vv[i]);
          lo[q * 4 + i] = bf16rn(vv[i] - bf16tof(hi[q * 4 + i]));
        }
      }
      *(uint4*)&Ah[r * 72 + kq] = *(uint4*)&hi[0]; *(uint4*)&Ah[r * 72 + kq + 8] = *(uint4*)&hi[8];
      *(uint4*)&Al[r * 72 + kq] = *(uint4*)&lo[0]; *(uint4*)&Al[r * 72 + kq + 8] = *(uint4*)&lo[8];
    }
    {
      const float* bp = Bp + ((size_t)(n0 + r)) * Fn + kc + kq;
      unsigned short hi[16], lo[16];
      #pragma unroll
      for (int q = 0; q < 4; ++q) {
        float4 v = *(const float4*)(bp + q * 4);
        float vv[4] = {v.x, v.y, v.z, v.w};
        #pragma unroll
        for (int i = 0; i < 4; ++i) {
          hi[q * 4 + i] = bf16rn(vv[i]);
          lo[q * 4 + i] = bf16rn(vv[i] - bf16tof(hi[q * 4 + i]));
        }
      }
      *(uint4*)&Bh[r * 72 + kq] = *(uint4*)&hi[0]; *(uint4*)&Bh[r * 72 + kq + 8] = *(uint4*)&hi[8];
      *(uint4*)&Bl[r * 72 + kq] = *(uint4*)&lo[0]; *(uint4*)&Bl[r * 72 + kq + 8] = *(uint4*)&lo[8];
    }
    __syncthreads();
    #pragma unroll
    for (int ko = 0; ko < 64; ko += 32) {
      bf16x8 ah[2], al[2], bh[2], bl[2];
      #pragma unroll
      for (int mi = 0; mi < 2; ++mi) {
        int ra = (mo + mi * 16 + l15) * 72 + ko + quad * 8;
        ah[mi] = *(const bf16x8*)&Ah[ra]; al[mi] = *(const bf16x8*)&Al[ra];
      }
      #pragma unroll
      for (int nj = 0; nj < 2; ++nj) {
        int rb = (no + nj * 16 + l15) * 72 + ko + quad * 8;
        bh[nj] = *(const bf16x8*)&Bh[rb]; bl[nj] = *(const bf16x8*)&Bl[rb];
      }
      #pragma unroll
      for (int mi = 0; mi < 2; ++mi)
        #pragma unroll
        for (int nj = 0; nj < 2; ++nj) {
          acc[mi][nj] = __builtin_amdgcn_mfma_f32_16x16x32_bf16(ah[mi], bh[nj], acc[mi][nj], 0, 0, 0);
          acc[mi][nj] = __builtin_amdgcn_mfma_f32_16x16x32_bf16(ah[mi], bl[nj], acc[mi][nj], 0, 0, 0);
          acc[mi][nj] = __builtin_amdgcn_mfma_f32_16x16x32_bf16(al[mi], bh[nj], acc[mi][nj], 0, 0, 0);
        }
    }
  }
  const int bb = n0 / LXn;                      // job-b: 64-tile never straddles b
  #pragma unroll
  for (int mi = 0; mi < 2; ++mi)
    #pragma unroll
    for (int nj = 0; nj < 2; ++nj)
      #pragma unroll
      for (int rr = 0; rr < 4; ++rr) {
        int row = m0 + mo + mi * 16 + quad * 4 + rr;
        int col = n0 + no + nj * 16 + l15;
        float val = __builtin_amdgcn_exp2f(ksc * acc[mi][nj][rr]);
        if (jobA) ey[(size_t)row * Hn + col] = val;
        else      exT[(size_t)bb * Hn * LXn + (size_t)row * LXn + (col - bb * LXn)] = val;
      }
}

// ---------------------------------------------------------------- kernel 2
// acc[j,l] = sum_h (-2 vm_h)/(ex*ey+1)  (4-way rcp pairing, 4.5 slots/elem),
// then fused block softmax over l and bf16 hi/lo split of the attention weights.
__global__ __launch_bounds__(384) void score_sm(
    const float* __restrict__ exT, const float* __restrict__ ey,
    const float* __restrict__ vm, unsigned short* __restrict__ ahi,
    unsigned short* __restrict__ alo)
{
  __shared__ float ey3[3][256], vm2[256], redA[3][8], redB[3][8];
  const int tid = threadIdx.x;
  const int b = blockIdx.y, j0 = blockIdx.x * 3;
  for (int i = tid; i < 768; i += 384)
    ey3[i >> 8][i & 255] = ey[(size_t)(b * LYn + j0 + (i >> 8)) * Hn + (i & 255)];
  if (tid < 256) vm2[tid] = -2.0f * vm[tid];
  __syncthreads();

  const float* exb = exT + (size_t)b * Hn * LXn + tid;
  float acc[3] = {0.f, 0.f, 0.f};
  for (int h = 0; h < Hn; h += 8) {
    float ev[8];
    #pragma unroll
    for (int u = 0; u < 8; ++u) ev[u] = exb[(size_t)(h + u) * LXn];
    float4 va = *(const float4*)&vm2[h], vb = *(const float4*)&vm2[h + 4];
    #pragma unroll
    for (int jj = 0; jj < 3; ++jj) {
      float4 ea = *(const float4*)&ey3[jj][h], eb = *(const float4*)&ey3[jj][h + 4];
      {
        float A = fmaf(ev[0], ea.x, 1.f), B = fmaf(ev[1], ea.y, 1.f);
        float C = fmaf(ev[2], ea.z, 1.f), D = fmaf(ev[3], ea.w, 1.f);
        float AB = A * B, CD = C * D;
        float n1 = fmaf(va.y, A, va.x * B), n2 = fmaf(va.w, C, va.z * D);
        float num = fmaf(n2, AB, n1 * CD);
        acc[jj] = fmaf(num, __builtin_amdgcn_rcpf(AB * CD), acc[jj]);
      }
      {
        float A = fmaf(ev[4], eb.x, 1.f), B = fmaf(ev[5], eb.y, 1.f);
        float C = fmaf(ev[6], eb.z, 1.f), D = fmaf(ev[7], eb.w, 1.f);
        float AB = A * B, CD = C * D;
        float n1 = fmaf(vb.y, A, vb.x * B), n2 = fmaf(vb.w, C, vb.z * D);
        float num = fmaf(n2, AB, n1 * CD);
        acc[jj] = fmaf(num, __builtin_amdgcn_rcpf(AB * CD), acc[jj]);
      }
    }
  }

  const int lane = tid & 63, wid = tid >> 6;
  float e[3];
  #pragma unroll
  for (int jj = 0; jj < 3; ++jj) {
    float t = acc[jj];
    #pragma unroll
    for (int off = 32; off; off >>= 1) t = fmaxf(t, __shfl_xor(t, off));
    if (lane == 0) redA[jj][wid] = t;
  }
  __syncthreads();
  #pragma unroll
  for (int jj = 0; jj < 3; ++jj) {
    float m = redA[jj][0];
    #pragma unroll
    for (int ww = 1; ww < 6; ++ww) m = fmaxf(m, redA[jj][ww]);
    float s = __builtin_amdgcn_exp2f((acc[jj] - m) * LOG2E);
    e[jj] = s;
    #pragma unroll
    for (int off = 32; off; off >>= 1) s += __shfl_xor(s, off);
    if (lane == 0) redB[jj][wid] = s;
  }
  __syncthreads();
  #pragma unroll
  for (int jj = 0; jj < 3; ++jj) {
    float tot = redB[jj][0];
    #pragma unroll
    for (int ww = 1; ww < 6; ++ww) tot += redB[jj][ww];
    float a = e[jj] * __builtin_amdgcn_rcpf(tot);
    unsigned short h = bf16rn(a);
    unsigned short l2 = bf16rn(a - bf16tof(h));
    size_t o = (size_t)(b * LYn + j0 + jj) * LXn + tid;
    ahi[o] = h; alo[o] = l2;
  }
}

// ---------------------------------------------------------------- kernel 3
// qtm[b,j,f] = sum_l a[j,l]*x[l,f] via MFMA: A = a (split), Bt = xT (split).
__global__ __launch_bounds__(256) void qtm(
    const unsigned short* __restrict__ ahi, const unsigned short* __restrict__ alo,
    const unsigned short* __restrict__ xThi, const unsigned short* __restrict__ xTlo,
    float* __restrict__ out)
{
  __shared__ char smem[36864];
  unsigned short* LAh = (unsigned short*)smem;
  unsigned short* LAl = LAh + 64 * 72;
  unsigned short* LBh = LAl + 64 * 72;
  unsigned short* LBl = LBh + 64 * 72;

  const int bid = blockIdx.x;
  const int b = bid / 48, t = bid % 48;
  const int m0 = (t / 8) * 64, n0 = (t % 8) * 64;   // m over j(384), n over f(512)
  const int tid = threadIdx.x;
  const int r = tid >> 2, kq = (tid & 3) * 16;
  const int w = tid >> 6, lane = tid & 63, quad = lane >> 4, l15 = lane & 15;
  const int mo = (w & 1) * 32, no = (w >> 1) * 32;
  f32x4 acc[2][2] = {};

  const unsigned short* Arh = ahi + ((size_t)(b * LYn + m0 + r)) * LXn + kq;
  const unsigned short* Arl = alo + ((size_t)(b * LYn + m0 + r)) * LXn + kq;
  const unsigned short* Brh = xThi + ((size_t)(b * Fn + n0 + r)) * LXn + kq;
  const unsigned short* Brl = xTlo + ((size_t)(b * Fn + n0 + r)) * LXn + kq;

  for (int kc = 0; kc < LXn; kc += 64) {
    __syncthreads();
    *(uint4*)&LAh[r * 72 + kq]     = *(const uint4*)(Arh + kc);
    *(uint4*)&LAh[r * 72 + kq + 8] = *(const uint4*)(Arh + kc + 8);
    *(uint4*)&LAl[r * 72 + kq]     = *(const uint4*)(Arl + kc);
    *(uint4*)&LAl[r * 72 + kq + 8] = *(const uint4*)(Arl + kc + 8);
    *(uint4*)&LBh[r * 72 + kq]     = *(const uint4*)(Brh + kc);
    *(uint4*)&LBh[r * 72 + kq + 8] = *(const uint4*)(Brh + kc + 8);
    *(uint4*)&LBl[r * 72 + kq]     = *(const uint4*)(Brl + kc);
    *(uint4*)&LBl[r * 72 + kq + 8] = *(const uint4*)(Brl + kc + 8);
    __syncthreads();
    #pragma unroll
    for (int ko = 0; ko < 64; ko += 32) {
      bf16x8 ah[2], al[2], bh[2], bl[2];
      #pragma unroll
      for (int mi = 0; mi < 2; ++mi) {
        int ra = (mo + mi * 16 + l15) * 72 + ko + quad * 8;
        ah[mi] = *(const bf16x8*)&LAh[ra]; al[mi] = *(const bf16x8*)&LAl[ra];
      }
      #pragma unroll
      for (int nj = 0; nj < 2; ++nj) {
        int rb = (no + nj * 16 + l15) * 72 + ko + quad * 8;
        bh[nj] = *(const bf16x8*)&LBh[rb]; bl[nj] = *(const bf16x8*)&LBl[rb];
      }
      #pragma unroll
      for (int mi = 0; mi < 2; ++mi)
        #pragma unroll
        for (int nj = 0; nj < 2; ++nj) {
          acc[mi][nj] = __builtin_amdgcn_mfma_f32_16x16x32_bf16(ah[mi], bh[nj], acc[mi][nj], 0, 0, 0);
          acc[mi][nj] = __builtin_amdgcn_mfma_f32_16x16x32_bf16(ah[mi], bl[nj], acc[mi][nj], 0, 0, 0);
          acc[mi][nj] = __builtin_amdgcn_mfma_f32_16x16x32_bf16(al[mi], bh[nj], acc[mi][nj], 0, 0, 0);
        }
    }
  }
  #pragma unroll
  for (int mi = 0; mi < 2; ++mi)
    #pragma unroll
    for (int nj = 0; nj < 2; ++nj)
      #pragma unroll
      for (int rr = 0; rr < 4; ++rr) {
        int row = m0 + mo + mi * 16 + quad * 4 + rr;   // j
        int col = n0 + no + nj * 16 + l15;             // f
        out[((size_t)(b * LYn + row)) * Fn + col] = acc[mi][nj][rr];
      }
}

extern "C" void kernel_launch(void* const* d_in, const int* in_sizes, int n_in,
                              void* d_out, int out_size, void* d_ws, size_t ws_size,
                              hipStream_t stream) {
  const float* x  = (const float*)d_in[0];
  const float* y  = (const float*)d_in[1];
  const float* Wm = (const float*)d_in[2];
  const float* vm = (const float*)d_in[3];
  float* outp = (float*)d_out;

  float* ey  = (float*)d_ws;                         // [1536][256] f32
  float* exT = ey + (size_t)1536 * 256;              // [4][256][384] f32
  unsigned short* xThi = (unsigned short*)(exT + (size_t)4 * 256 * 384);
  unsigned short* xTlo = xThi + (size_t)4 * 512 * 384;
  unsigned short* ahi  = xTlo + (size_t)4 * 512 * 384;
  unsigned short* alo  = ahi + (size_t)1536 * 384;   // total ~8.6 MB

  hipLaunchKernelGGL(k1, dim3(384), dim3(256), 0, stream, x, y, Wm, ey, exT, xThi, xTlo);
  hipLaunchKernelGGL(score_sm, dim3(128, 4), dim3(384), 0, stream, exT, ey, vm, ahi, alo);
  hipLaunchKernelGGL(qtm, dim3(192), dim3(256), 0, stream, ahi, alo, xThi, xTlo, outp);
}

// Round 5
// 103.466 us; speedup vs baseline: 1.6703x; 1.1185x over previous
//
#include <hip/hip_runtime.h>

#define LOG2E 1.4426950408889634f
#define K_SCALE 2.8853900817779268f   // 2*log2(e)

typedef __attribute__((ext_vector_type(8))) short bf16x8;
typedef __attribute__((ext_vector_type(4))) float f32x4;

constexpr int Bn = 4, LXn = 384, LYn = 384, Hn = 256, Fn = 512;

__device__ inline unsigned short bf16rn(float f) {
  unsigned u = __builtin_bit_cast(unsigned, f);
  u += 0x7fff + ((u >> 16) & 1);             // round-to-nearest-even
  return (unsigned short)(u >> 16);
}
__device__ inline float bf16tof(unsigned short h) {
  return __builtin_bit_cast(float, (unsigned)h << 16);
}

// ---------------------------------------------------------------- kernel 1
// blocks [0,96):   ey[m=(b,j)][h]  = exp2(-K * y.Wm^T)   (MFMA, split-bf16 3-product)
// blocks [96,192): exT[b][h][l]    = exp2(+K * Wm.x^T)
// blocks [192,384): transpose+split x -> xThi/xTlo[b][f][l]  (for qtm's B operand)
__global__ __launch_bounds__(256) void k1(
    const float* __restrict__ x, const float* __restrict__ y,
    const float* __restrict__ Wm, float* __restrict__ ey, float* __restrict__ exT,
    unsigned short* __restrict__ xThi, unsigned short* __restrict__ xTlo)
{
  __shared__ char smem[36864];
  const int tid = threadIdx.x;
  const int bid = blockIdx.x;

  if (bid >= 192) {                       // ---- transpose/split path ----
    float* T = (float*)smem;              // [64][65]
    const int pid = bid - 192;
    const int b = pid / 48, t = pid % 48;
    const int l0 = (t / 8) * 64, f0 = (t % 8) * 64;
    const int r = tid >> 2, cq = (tid & 3) * 16;
    const float* xp = x + ((size_t)(b * LXn + l0 + r)) * Fn + f0 + cq;
    #pragma unroll
    for (int q = 0; q < 4; ++q) {
      float4 v = *(const float4*)(xp + q * 4);
      T[r * 65 + cq + q * 4 + 0] = v.x; T[r * 65 + cq + q * 4 + 1] = v.y;
      T[r * 65 + cq + q * 4 + 2] = v.z; T[r * 65 + cq + q * 4 + 3] = v.w;
    }
    __syncthreads();
    const int fr = tid >> 2, lq = (tid & 3) * 16;
    unsigned short hi[16], lo[16];
    #pragma unroll
    for (int i = 0; i < 16; ++i) {
      float v = T[(lq + i) * 65 + fr];
      hi[i] = bf16rn(v);
      lo[i] = bf16rn(v - bf16tof(hi[i]));
    }
    size_t o = ((size_t)(b * Fn + f0 + fr)) * LXn + l0 + lq;
    *(uint4*)&xThi[o] = *(uint4*)&hi[0]; *(uint4*)&xThi[o + 8] = *(uint4*)&hi[8];
    *(uint4*)&xTlo[o] = *(uint4*)&lo[0]; *(uint4*)&xTlo[o + 8] = *(uint4*)&lo[8];
    return;
  }

  // ---- MFMA GEMM path ----
  unsigned short* Ah = (unsigned short*)smem;   // [64][72] bf16, pad 72 breaks conflicts
  unsigned short* Al = Ah + 64 * 72;
  unsigned short* Bh = Al + 64 * 72;
  unsigned short* Bl = Bh + 64 * 72;

  const float *Ap, *Bp; float ksc; bool jobA;
  int m0, n0;
  if (bid < 96) { jobA = true;  int mt = bid % 24, nt = bid / 24; m0 = mt * 64; n0 = nt * 64;
                  Ap = y;  Bp = Wm; ksc = -K_SCALE; }
  else          { jobA = false; int t = bid - 96; int mt = t & 3, nt = t >> 2; m0 = mt * 64; n0 = nt * 64;
                  Ap = Wm; Bp = x;  ksc =  K_SCALE; }

  const int r = tid >> 2, kq = (tid & 3) * 16;
  const int w = tid >> 6, lane = tid & 63, quad = lane >> 4, l15 = lane & 15;
  const int mo = (w & 1) * 32, no = (w >> 1) * 32;   // wave tile 32x32
  f32x4 acc[2][2] = {};

  for (int kc = 0; kc < Fn; kc += 64) {
    __syncthreads();
    {
      const float* ap = Ap + ((size_t)(m0 + r)) * Fn + kc + kq;
      unsigned short hi[16], lo[16];
      #pragma unroll
      for (int q = 0; q < 4; ++q) {
        float4 v = *(const float4*)(ap + q * 4);
        float vv[4] = {v.x, v.y, v.z, v.w};
        #pragma unroll
        for (int i = 0; i < 4; ++i) {
          hi[q * 4 + i] = bf16rn(vv[i]);
          lo[q * 4 + i] = bf16rn(vv[i] - bf16tof(hi[q * 4 + i]));
        }
      }
      *(uint4*)&Ah[r * 72 + kq] = *(uint4*)&hi[0]; *(uint4*)&Ah[r * 72 + kq + 8] = *(uint4*)&hi[8];
      *(uint4*)&Al[r * 72 + kq] = *(uint4*)&lo[0]; *(uint4*)&Al[r * 72 + kq + 8] = *(uint4*)&lo[8];
    }
    {
      const float* bp = Bp + ((size_t)(n0 + r)) * Fn + kc + kq;
      unsigned short hi[16], lo[16];
      #pragma unroll
      for (int q = 0; q < 4; ++q) {
        float4 v = *(const float4*)(bp + q * 4);
        float vv[4] = {v.x, v.y, v.z, v.w};
        #pragma unroll
        for (int i = 0; i < 4; ++i) {
          hi[q * 4 + i] = bf16rn(vv[i]);
          lo[q * 4 + i] = bf16rn(vv[i] - bf16tof(hi[q * 4 + i]));
        }
      }
      *(uint4*)&Bh[r * 72 + kq] = *(uint4*)&hi[0]; *(uint4*)&Bh[r * 72 + kq + 8] = *(uint4*)&hi[8];
      *(uint4*)&Bl[r * 72 + kq] = *(uint4*)&lo[0]; *(uint4*)&Bl[r * 72 + kq + 8] = *(uint4*)&lo[8];
    }
    __syncthreads();
    #pragma unroll
    for (int ko = 0; ko < 64; ko += 32) {
      bf16x8 ah[2], al[2], bh[2], bl[2];
      #pragma unroll
      for (int mi = 0; mi < 2; ++mi) {
        int ra = (mo + mi * 16 + l15) * 72 + ko + quad * 8;
        ah[mi] = *(const bf16x8*)&Ah[ra]; al[mi] = *(const bf16x8*)&Al[ra];
      }
      #pragma unroll
      for (int nj = 0; nj < 2; ++nj) {
        int rb = (no + nj * 16 + l15) * 72 + ko + quad * 8;
        bh[nj] = *(const bf16x8*)&Bh[rb]; bl[nj] = *(const bf16x8*)&Bl[rb];
      }
      #pragma unroll
      for (int mi = 0; mi < 2; ++mi)
        #pragma unroll
        for (int nj = 0; nj < 2; ++nj) {
          acc[mi][nj] = __builtin_amdgcn_mfma_f32_16x16x32_bf16(ah[mi], bh[nj], acc[mi][nj], 0, 0, 0);
          acc[mi][nj] = __builtin_amdgcn_mfma_f32_16x16x32_bf16(ah[mi], bl[nj], acc[mi][nj], 0, 0, 0);
          acc[mi][nj] = __builtin_amdgcn_mfma_f32_16x16x32_bf16(al[mi], bh[nj], acc[mi][nj], 0, 0, 0);
        }
    }
  }
  const int bb = n0 / LXn;                      // job-b: 64-tile never straddles b
  #pragma unroll
  for (int mi = 0; mi < 2; ++mi)
    #pragma unroll
    for (int nj = 0; nj < 2; ++nj)
      #pragma unroll
      for (int rr = 0; rr < 4; ++rr) {
        int row = m0 + mo + mi * 16 + quad * 4 + rr;
        int col = n0 + no + nj * 16 + l15;
        float val = __builtin_amdgcn_exp2f(ksc * acc[mi][nj][rr]);
        if (jobA) ey[(size_t)row * Hn + col] = val;
        else      exT[(size_t)bb * Hn * LXn + (size_t)row * LXn + (col - bb * LXn)] = val;
      }
}

// ---------------------------------------------------------------- kernel 2
// score_v2: LDS-pipe-light score + fused softmax.
// 256 blocks x 768 threads; thread = (lq = tid%96 -> 4 l's, hg = tid/96 -> 32 h's).
// Per 4h-step: 4 global b128 ex loads feed 6j x 4l x 4h = 96 elems;
// ey/vm via 7 broadcast LDS b128. 4-way rcp pairing. Then fold partials
// 8->4->1 in LDS, block softmax per j, write a as bf16 hi/lo planes.
__global__ __launch_bounds__(768) void score_v2(
    const float* __restrict__ exT, const float* __restrict__ ey,
    const float* __restrict__ vm, unsigned short* __restrict__ ahi,
    unsigned short* __restrict__ alo)
{
  __shared__ float ey6[6 * 256];
  __shared__ float vms[256];
  __shared__ __align__(16) float part[4 * 6 * 384];   // 36.9 KB
  __shared__ float red[768];
  __shared__ float red2[2][48];

  const int tid = threadIdx.x;
  const int b = blockIdx.y, j0 = blockIdx.x * 6;
  const int lq = tid % 96, hg = tid / 96;
  const int hb = hg * 32;

  for (int i = tid; i < 6 * 256; i += 768)
    ey6[i] = ey[(size_t)(b * LYn + j0 + (i >> 8)) * Hn + (i & 255)];
  if (tid < 256) vms[tid] = -2.0f * vm[tid];
  __syncthreads();

  const float* exb = exT + (size_t)b * Hn * LXn + (size_t)hb * LXn + lq * 4;
  float acc[6][4] = {};

  for (int hs = 0; hs < 32; hs += 4) {
    float4 e0 = *(const float4*)(exb + (size_t)(hs + 0) * LXn);
    float4 e1 = *(const float4*)(exb + (size_t)(hs + 1) * LXn);
    float4 e2 = *(const float4*)(exb + (size_t)(hs + 2) * LXn);
    float4 e3 = *(const float4*)(exb + (size_t)(hs + 3) * LXn);
    const float* E0 = (const float*)&e0; const float* E1 = (const float*)&e1;
    const float* E2 = (const float*)&e2; const float* E3 = (const float*)&e3;
    float4 v4 = *(const float4*)&vms[hb + hs];
    #pragma unroll
    for (int j = 0; j < 6; ++j) {
      float4 y4 = *(const float4*)&ey6[j * 256 + hb + hs];
      #pragma unroll
      for (int i = 0; i < 4; ++i) {
        float A = fmaf(E0[i], y4.x, 1.f), B = fmaf(E1[i], y4.y, 1.f);
        float C = fmaf(E2[i], y4.z, 1.f), D = fmaf(E3[i], y4.w, 1.f);
        float AB = A * B, CD = C * D;
        float n1 = fmaf(v4.y, A, v4.x * B), n2 = fmaf(v4.w, C, v4.z * D);
        float num = fmaf(n2, AB, n1 * CD);
        acc[j][i] = fmaf(num, __builtin_amdgcn_rcpf(AB * CD), acc[j][i]);
      }
    }
  }

  // fold 8 hg-planes -> 4 (in LDS), keeping hg<4 sums in registers
  if (hg >= 4) {
    #pragma unroll
    for (int j = 0; j < 6; ++j)
      *(float4*)&part[((hg - 4) * 6 + j) * 384 + lq * 4] = *(const float4*)&acc[j][0];
  }
  __syncthreads();
  if (hg < 4) {
    #pragma unroll
    for (int j = 0; j < 6; ++j) {
      float4 o = *(const float4*)&part[(hg * 6 + j) * 384 + lq * 4];
      acc[j][0] += o.x; acc[j][1] += o.y; acc[j][2] += o.z; acc[j][3] += o.w;
      *(float4*)&part[(hg * 6 + j) * 384 + lq * 4] = *(const float4*)&acc[j][0];
    }
  }
  __syncthreads();

  // stage 1: final 4-way sum; per-thread max
  float4 s4 = make_float4(0, 0, 0, 0);
  const int js = tid / 96 >= 6 ? 0 : tid / 96;   // j for stages (t<576 active)
  const int ls = lq;
  if (tid < 576) {
    const int j = tid / 96;
    #pragma unroll
    for (int p = 0; p < 4; ++p) {
      float4 o = *(const float4*)&part[(p * 6 + j) * 384 + ls * 4];
      s4.x += o.x; s4.y += o.y; s4.z += o.z; s4.w += o.w;
    }
    red[tid] = fmaxf(fmaxf(s4.x, s4.y), fmaxf(s4.z, s4.w));
  }
  __syncthreads();
  if (tid < 48) {
    const int j = tid / 8, seg = tid % 8;
    float m = red[j * 96 + seg * 12];
    #pragma unroll
    for (int i = 1; i < 12; ++i) m = fmaxf(m, red[j * 96 + seg * 12 + i]);
    red2[0][tid] = m;
  }
  __syncthreads();
  float4 e4;
  if (tid < 576) {
    const int j = tid / 96;
    float m = red2[0][j * 8];
    #pragma unroll
    for (int i = 1; i < 8; ++i) m = fmaxf(m, red2[0][j * 8 + i]);
    e4.x = __builtin_amdgcn_exp2f((s4.x - m) * LOG2E);
    e4.y = __builtin_amdgcn_exp2f((s4.y - m) * LOG2E);
    e4.z = __builtin_amdgcn_exp2f((s4.z - m) * LOG2E);
    e4.w = __builtin_amdgcn_exp2f((s4.w - m) * LOG2E);
    red[tid] = e4.x + e4.y + e4.z + e4.w;
  }
  __syncthreads();
  if (tid < 48) {
    const int j = tid / 8, seg = tid % 8;
    float t = 0.f;
    #pragma unroll
    for (int i = 0; i < 12; ++i) t += red[j * 96 + seg * 12 + i];
    red2[1][tid] = t;
  }
  __syncthreads();
  if (tid < 576) {
    const int j = tid / 96;
    float tot = 0.f;
    #pragma unroll
    for (int i = 0; i < 8; ++i) tot += red2[1][j * 8 + i];
    float r = __builtin_amdgcn_rcpf(tot);
    unsigned short h[4], l[4];
    const float* ep = (const float*)&e4;
    #pragma unroll
    for (int i = 0; i < 4; ++i) {
      float a = ep[i] * r;
      h[i] = bf16rn(a);
      l[i] = bf16rn(a - bf16tof(h[i]));
    }
    size_t o = (size_t)(b * LYn + j0 + j) * LXn + ls * 4;
    *(uint2*)&ahi[o] = *(uint2*)&h[0];
    *(uint2*)&alo[o] = *(uint2*)&l[0];
  }
}

// ---------------------------------------------------------------- kernel 3
// qtm[b,j,f] = sum_l a[j,l]*x[l,f] via MFMA: A = a (split), Bt = xT (split).
__global__ __launch_bounds__(256) void qtm(
    const unsigned short* __restrict__ ahi, const unsigned short* __restrict__ alo,
    const unsigned short* __restrict__ xThi, const unsigned short* __restrict__ xTlo,
    float* __restrict__ out)
{
  __shared__ char smem[36864];
  unsigned short* LAh = (unsigned short*)smem;
  unsigned short* LAl = LAh + 64 * 72;
  unsigned short* LBh = LAl + 64 * 72;
  unsigned short* LBl = LBh + 64 * 72;

  const int bid = blockIdx.x;
  const int b = bid / 48, t = bid % 48;
  const int m0 = (t / 8) * 64, n0 = (t % 8) * 64;   // m over j(384), n over f(512)
  const int tid = threadIdx.x;
  const int r = tid >> 2, kq = (tid & 3) * 16;
  const int w = tid >> 6, lane = tid & 63, quad = lane >> 4, l15 = lane & 15;
  const int mo = (w & 1) * 32, no = (w >> 1) * 32;
  f32x4 acc[2][2] = {};

  const unsigned short* Arh = ahi + ((size_t)(b * LYn + m0 + r)) * LXn + kq;
  const unsigned short* Arl = alo + ((size_t)(b * LYn + m0 + r)) * LXn + kq;
  const unsigned short* Brh = xThi + ((size_t)(b * Fn + n0 + r)) * LXn + kq;
  const unsigned short* Brl = xTlo + ((size_t)(b * Fn + n0 + r)) * LXn + kq;

  for (int kc = 0; kc < LXn; kc += 64) {
    __syncthreads();
    *(uint4*)&LAh[r * 72 + kq]     = *(const uint4*)(Arh + kc);
    *(uint4*)&LAh[r * 72 + kq + 8] = *(const uint4*)(Arh + kc + 8);
    *(uint4*)&LAl[r * 72 + kq]     = *(const uint4*)(Arl + kc);
    *(uint4*)&LAl[r * 72 + kq + 8] = *(const uint4*)(Arl + kc + 8);
    *(uint4*)&LBh[r * 72 + kq]     = *(const uint4*)(Brh + kc);
    *(uint4*)&LBh[r * 72 + kq + 8] = *(const uint4*)(Brh + kc + 8);
    *(uint4*)&LBl[r * 72 + kq]     = *(const uint4*)(Brl + kc);
    *(uint4*)&LBl[r * 72 + kq + 8] = *(const uint4*)(Brl + kc + 8);
    __syncthreads();
    #pragma unroll
    for (int ko = 0; ko < 64; ko += 32) {
      bf16x8 ah[2], al[2], bh[2], bl[2];
      #pragma unroll
      for (int mi = 0; mi < 2; ++mi) {
        int ra = (mo + mi * 16 + l15) * 72 + ko + quad * 8;
        ah[mi] = *(const bf16x8*)&LAh[ra]; al[mi] = *(const bf16x8*)&LAl[ra];
      }
      #pragma unroll
      for (int nj = 0; nj < 2; ++nj) {
        int rb = (no + nj * 16 + l15) * 72 + ko + quad * 8;
        bh[nj] = *(const bf16x8*)&LBh[rb]; bl[nj] = *(const bf16x8*)&LBl[rb];
      }
      #pragma unroll
      for (int mi = 0; mi < 2; ++mi)
        #pragma unroll
        for (int nj = 0; nj < 2; ++nj) {
          acc[mi][nj] = __builtin_amdgcn_mfma_f32_16x16x32_bf16(ah[mi], bh[nj], acc[mi][nj], 0, 0, 0);
          acc[mi][nj] = __builtin_amdgcn_mfma_f32_16x16x32_bf16(ah[mi], bl[nj], acc[mi][nj], 0, 0, 0);
          acc[mi][nj] = __builtin_amdgcn_mfma_f32_16x16x32_bf16(al[mi], bh[nj], acc[mi][nj], 0, 0, 0);
        }
    }
  }
  #pragma unroll
  for (int mi = 0; mi < 2; ++mi)
    #pragma unroll
    for (int nj = 0; nj < 2; ++nj)
      #pragma unroll
      for (int rr = 0; rr < 4; ++rr) {
        int row = m0 + mo + mi * 16 + quad * 4 + rr;   // j
        int col = n0 + no + nj * 16 + l15;             // f
        out[((size_t)(b * LYn + row)) * Fn + col] = acc[mi][nj][rr];
      }
}

extern "C" void kernel_launch(void* const* d_in, const int* in_sizes, int n_in,
                              void* d_out, int out_size, void* d_ws, size_t ws_size,
                              hipStream_t stream) {
  const float* x  = (const float*)d_in[0];
  const float* y  = (const float*)d_in[1];
  const float* Wm = (const float*)d_in[2];
  const float* vm = (const float*)d_in[3];
  float* outp = (float*)d_out;

  float* ey  = (float*)d_ws;                         // [1536][256] f32
  float* exT = ey + (size_t)1536 * 256;              // [4][256][384] f32
  unsigned short* xThi = (unsigned short*)(exT + (size_t)4 * 256 * 384);
  unsigned short* xTlo = xThi + (size_t)4 * 512 * 384;
  unsigned short* ahi  = xTlo + (size_t)4 * 512 * 384;
  unsigned short* alo  = ahi + (size_t)1536 * 384;   // total ~8.6 MB

  hipLaunchKernelGGL(k1, dim3(384), dim3(256), 0, stream, x, y, Wm, ey, exT, xThi, xTlo);
  hipLaunchKernelGGL(score_v2, dim3(64, 4), dim3(768), 0, stream, exT, ey, vm, ahi, alo);
  hipLaunchKernelGGL(qtm, dim3(192), dim3(256), 0, stream, ahi, alo, xThi, xTlo, outp);
}